// Round 1
// baseline (302.888 us; speedup 1.0000x reference)
//
#include <hip/hip_runtime.h>
#include <cstdint>
#include <cstddef>

typedef unsigned short u16;
typedef __attribute__((ext_vector_type(8))) short short8;
typedef __attribute__((ext_vector_type(4))) short short4v;
typedef __attribute__((ext_vector_type(8))) unsigned short ushort8v;
typedef __attribute__((ext_vector_type(4))) unsigned short ushort4v;
typedef __attribute__((ext_vector_type(4))) float f32x4;

#define LOG2E 1.44269504088896340736f

// ---- helpers -------------------------------------------------------------

__device__ __forceinline__ u16 f2bf(float f) {
  unsigned int u = __builtin_bit_cast(unsigned int, f);
  u += 0x7FFFu + ((u >> 16) & 1u);   // RNE
  return (u16)(u >> 16);
}

__device__ __forceinline__ void async16(const void* g, void* l) {
  __builtin_amdgcn_global_load_lds(
      (const __attribute__((address_space(1))) unsigned int*)g,
      (__attribute__((address_space(3))) unsigned int*)l, 16, 0, 0);
}

// ---- fp32 -> bf16 convert ------------------------------------------------

__global__ void cvt_f32_bf16(const float* __restrict__ in, u16* __restrict__ out, int n) {
  int i = (blockIdx.x * 256 + threadIdx.x) * 4;
  if (i >= n) return;
  float4 v = *(const float4*)(in + i);
  ushort4v o;
  o[0] = f2bf(v.x); o[1] = f2bf(v.y); o[2] = f2bf(v.z); o[3] = f2bf(v.w);
  *(ushort4v*)(out + i) = o;
}

// ---- bf16 GEMM: C[M,N] = A[M,K] * W[N,K]^T  (m97-style 128^2 tile) -------
// MODE 0: bf16 output permuted to [B,H,S,HD]   MODE 1: f32 output [M,N]

template<int MODE>
__global__ __launch_bounds__(256, 2) void gemm_bt(
    const u16* __restrict__ A, const u16* __restrict__ Bw,
    void* __restrict__ Cout, int M, int N, int K)
{
  const int t = threadIdx.x;
  const int lane = t & 63, w = t >> 6;
  const int li = lane & 15, g = lane >> 4;
  const int wr = w >> 1, wc = w & 1;
  const int brow = blockIdx.y * 128, bcol = blockIdx.x * 128;

  __shared__ u16 As[128 * 32];
  __shared__ u16 Bs[128 * 32];

  f32x4 acc[4][4];
#pragma unroll
  for (int i = 0; i < 4; ++i)
#pragma unroll
    for (int j = 0; j < 4; ++j) acc[i][j] = f32x4{0.f, 0.f, 0.f, 0.f};

  // LDS XOR swizzle (rows are 64B -> row&3 on the 16B slot), applied by
  // pre-swizzling the global SOURCE (linear global_load_lds dest, rule #21).
  for (int k0 = 0; k0 < K; k0 += 32) {
#pragma unroll
    for (int L = 0; L < 2; ++L) {
      const int f = t + 256 * L;
      const int row = f >> 2;
      const int cb = ((f & 3) * 16) ^ ((row & 3) << 4);   // swizzled byte-in-row
      async16(A + (size_t)(brow + row) * K + k0 + (cb >> 1),
              &As[(w * 64 + 256 * L) * 8]);
      async16(Bw + (size_t)(bcol + row) * K + k0 + (cb >> 1),
              &Bs[(w * 64 + 256 * L) * 8]);
    }
    __syncthreads();
    short8 af[4], bfr[4];
    const int ksw = (g * 8) ^ ((li & 3) << 3);            // swizzled k-offset (elems)
#pragma unroll
    for (int mt = 0; mt < 4; ++mt)
      af[mt] = *(const short8*)&As[(wr * 64 + mt * 16 + li) * 32 + ksw];
#pragma unroll
    for (int nt = 0; nt < 4; ++nt)
      bfr[nt] = *(const short8*)&Bs[(wc * 64 + nt * 16 + li) * 32 + ksw];
#pragma unroll
    for (int mt = 0; mt < 4; ++mt)
#pragma unroll
      for (int nt = 0; nt < 4; ++nt)
        acc[mt][nt] = __builtin_amdgcn_mfma_f32_16x16x32_bf16(af[mt], bfr[nt], acc[mt][nt], 0, 0, 0);
    __syncthreads();
  }

#pragma unroll
  for (int mt = 0; mt < 4; ++mt)
#pragma unroll
    for (int nt = 0; nt < 4; ++nt) {
      const int col = bcol + wc * 64 + nt * 16 + li;
#pragma unroll
      for (int r = 0; r < 4; ++r) {
        const int row = brow + wr * 64 + mt * 16 + g * 4 + r;
        const float v = acc[mt][nt][r];
        if (MODE == 0) {
          const int b = row >> 11, s = row & 2047;
          const int h = col >> 6, hd = col & 63;
          ((u16*)Cout)[(((size_t)(b * 16 + h) * 2048) + s) * 64 + hd] = f2bf(v);
        } else {
          ((float*)Cout)[(size_t)row * N + col] = v;
        }
      }
    }
}

// ---- V [B,H,S,HD] -> VT [B,H,HD,S] ---------------------------------------

__global__ __launch_bounds__(256) void transpose_hd_s(
    const u16* __restrict__ V, u16* __restrict__ VT)
{
  const int sb = blockIdx.x;   // 0..31 (s tile)
  const int bh = blockIdx.y;   // 0..63
  __shared__ u16 tile[64 * 72];
  const int t = threadIdx.x;
  const int r = t >> 3;          // 0..31
  const int c8 = (t & 7) * 8;
  const size_t base = (size_t)bh * 2048 * 64;
#pragma unroll
  for (int half = 0; half < 2; ++half) {
    const int row = r + 32 * half;   // s within tile
    ushort8v v = *(const ushort8v*)(V + base + (size_t)(sb * 64 + row) * 64 + c8);
    *(ushort8v*)&tile[row * 72 + c8] = v;
  }
  __syncthreads();
#pragma unroll
  for (int half = 0; half < 2; ++half) {
    const int hd = r + 32 * half;
    ushort8v o;
#pragma unroll
    for (int j = 0; j < 8; ++j) o[j] = tile[(c8 + j) * 72 + hd];
    *(ushort8v*)(VT + base + (size_t)hd * 2048 + sb * 64 + c8) = o;
  }
}

// ---- causal flash attention ----------------------------------------------
// Q,K: [B,H,S,HD] bf16   VT: [B,H,HD,S] bf16   Oattn: [B,S,D] bf16
// Computes S^T = mfma(K, Q) so each lane owns one q-row (i = lane&15).

__global__ __launch_bounds__(256, 2) void flash_attn(
    const u16* __restrict__ Qp, const u16* __restrict__ Kp,
    const u16* __restrict__ VTp, u16* __restrict__ Oattn)
{
  const int qb = blockIdx.x;   // 0..31  (q tile of 64 rows)
  const int bh = blockIdx.y;   // 0..63
  const int t = threadIdx.x;
  const int lane = t & 63, w = t >> 6;
  const int li = lane & 15, g = lane >> 4;

  __shared__ u16 Kl[64 * 64];   // [kv][hd], rows 128B, XOR-swizzled
  __shared__ u16 Vl[64 * 64];   // [hd][kv], rows 128B, XOR-swizzled

  const size_t bh_off = (size_t)bh * (2048 * 64);
  const int qrow = qb * 64 + w * 16 + li;

  short8 qf[2];
  {
    const u16* qp = Qp + bh_off + (size_t)qrow * 64 + g * 8;
    qf[0] = *(const short8*)qp;
    qf[1] = *(const short8*)(qp + 32);
  }

  f32x4 o_acc[4];
#pragma unroll
  for (int i = 0; i < 4; ++i) o_acc[i] = f32x4{0.f, 0.f, 0.f, 0.f};
  float m_i = -1e30f, l_i = 0.f;

  for (int jb = 0; jb <= qb; ++jb) {
#pragma unroll
    for (int L = 0; L < 2; ++L) {
      const int f = t + 256 * L;
      // K tile is contiguous 8KB in global; swizzle bits 4-6 of tile byte addr
      const int kbyte = (f * 16) ^ (((f >> 3) & 7) << 4);
      async16(Kp + bh_off + (size_t)jb * 4096 + (kbyte >> 1),
              &Kl[(w * 64 + 256 * L) * 8]);
      // VT tile: row = hd (global stride 2048), col = s
      const int vrow = f >> 3;
      const int vb = ((f & 7) * 16) ^ ((vrow & 7) << 4);
      async16(VTp + bh_off + (size_t)vrow * 2048 + jb * 64 + (vb >> 1),
              &Vl[(w * 64 + 256 * L) * 8]);
    }
    __syncthreads();

    // ---- S^T = K * Q^T  (tiles jt over kv, cols = 16 q rows of this wave)
    f32x4 s_acc[4];
#pragma unroll
    for (int jt = 0; jt < 4; ++jt) s_acc[jt] = f32x4{0.f, 0.f, 0.f, 0.f};
    const int ksw = (li & 7) << 3;   // element-space XOR
#pragma unroll
    for (int kc = 0; kc < 2; ++kc) {
#pragma unroll
      for (int jt = 0; jt < 4; ++jt) {
        short8 kf = *(const short8*)&Kl[(jt * 16 + li) * 64 + ((kc * 32 + g * 8) ^ ksw)];
        s_acc[jt] = __builtin_amdgcn_mfma_f32_16x16x32_bf16(kf, qf[kc], s_acc[jt], 0, 0, 0);
      }
    }

    // ---- scale + causal mask + online softmax (lane owns q-row i = li)
    float p[4][4];
    float mx = -1e30f;
    const bool diag = (jb == qb);
#pragma unroll
    for (int jt = 0; jt < 4; ++jt)
#pragma unroll
      for (int r = 0; r < 4; ++r) {
        float s = s_acc[jt][r] * 0.125f;
        if (diag && (jt * 16 + g * 4 + r > w * 16 + li)) s = -1e30f;
        p[jt][r] = s;
        mx = fmaxf(mx, s);
      }
    mx = fmaxf(mx, __shfl_xor(mx, 16));
    mx = fmaxf(mx, __shfl_xor(mx, 32));
    const float m_new = fmaxf(m_i, mx);
    const float corr = exp2f((m_i - m_new) * LOG2E);
    float ps = 0.f;
#pragma unroll
    for (int jt = 0; jt < 4; ++jt)
#pragma unroll
      for (int r = 0; r < 4; ++r) {
        p[jt][r] = exp2f((p[jt][r] - m_new) * LOG2E);
        ps += p[jt][r];
      }
    ps += __shfl_xor(ps, 16);
    ps += __shfl_xor(ps, 32);
    l_i = l_i * corr + ps;
    m_i = m_new;
#pragma unroll
    for (int dt = 0; dt < 4; ++dt) o_acc[dt] *= corr;

    // ---- P -> bf16 B-fragments (j_map(g,m) = 32kc + 16*(m/4) + 4g + m%4)
    short8 pf[2];
#pragma unroll
    for (int kc = 0; kc < 2; ++kc)
#pragma unroll
      for (int m = 0; m < 4; ++m) {
        pf[kc][m]     = (short)f2bf(p[2 * kc][m]);
        pf[kc][m + 4] = (short)f2bf(p[2 * kc + 1][m]);
      }

    // ---- O^T += V^T * P^T  (A-frag loaded with the SAME j_map)
#pragma unroll
    for (int kc = 0; kc < 2; ++kc)
#pragma unroll
      for (int dt = 0; dt < 4; ++dt) {
        const int rowb = (dt * 16 + li) * 64;
        short4v v0 = *(const short4v*)&Vl[rowb + ((kc * 32 + g * 4) ^ ksw)];
        short4v v1 = *(const short4v*)&Vl[rowb + ((kc * 32 + 16 + g * 4) ^ ksw)];
        short8 vf = __builtin_shufflevector(v0, v1, 0, 1, 2, 3, 4, 5, 6, 7);
        o_acc[dt] = __builtin_amdgcn_mfma_f32_16x16x32_bf16(vf, pf[kc], o_acc[dt], 0, 0, 0);
      }
    __syncthreads();
  }

  // ---- epilogue: O[i][d] = o^T/l, write [B,S,D] (lane's i = li, d = dt*16+4g+r)
  const float inv_l = 1.f / l_i;
  const int b = bh >> 4, h = bh & 15;
  u16* op = Oattn + ((size_t)(b * 2048 + qrow)) * 1024 + h * 64;
#pragma unroll
  for (int dt = 0; dt < 4; ++dt) {
    ushort4v st;
#pragma unroll
    for (int r = 0; r < 4; ++r) st[r] = f2bf(o_acc[dt][r] * inv_l);
    *(ushort4v*)(op + dt * 16 + g * 4) = st;
  }
}

// ---- launch --------------------------------------------------------------

extern "C" void kernel_launch(void* const* d_in, const int* in_sizes, int n_in,
                              void* d_out, int out_size, void* d_ws, size_t ws_size,
                              hipStream_t stream) {
  const float* x  = (const float*)d_in[0];
  const float* Wq = (const float*)d_in[1];
  const float* Wk = (const float*)d_in[2];
  const float* Wv = (const float*)d_in[3];
  const float* Wo = (const float*)d_in[4];

  const size_t NX = 8388608;   // B*S*D
  const size_t NW = 1048576;   // D*D

  u16* xb  = (u16*)d_ws;
  u16* wqb = xb + NX;
  u16* wkb = wqb + NW;
  u16* wvb = wkb + NW;
  u16* wob = wvb + NW;
  u16* Qb  = wob + NW;
  u16* Kb  = Qb + NX;
  u16* Vb  = Kb + NX;
  u16* VTb = Vb + NX;
  u16* attnb = Vb;             // V natural is dead after transpose; reuse

  cvt_f32_bf16<<<8192, 256, 0, stream>>>(x,  xb,  (int)NX);
  cvt_f32_bf16<<<1024, 256, 0, stream>>>(Wq, wqb, (int)NW);
  cvt_f32_bf16<<<1024, 256, 0, stream>>>(Wk, wkb, (int)NW);
  cvt_f32_bf16<<<1024, 256, 0, stream>>>(Wv, wvb, (int)NW);
  cvt_f32_bf16<<<1024, 256, 0, stream>>>(Wo, wob, (int)NW);

  dim3 gg(8, 64);
  gemm_bt<0><<<gg, 256, 0, stream>>>(xb, wqb, Qb, 8192, 1024, 1024);
  gemm_bt<0><<<gg, 256, 0, stream>>>(xb, wkb, Kb, 8192, 1024, 1024);
  gemm_bt<0><<<gg, 256, 0, stream>>>(xb, wvb, Vb, 8192, 1024, 1024);

  transpose_hd_s<<<dim3(32, 64), 256, 0, stream>>>(Vb, VTb);
  flash_attn<<<dim3(32, 64), 256, 0, stream>>>(Qb, Kb, VTb, attnb);

  gemm_bt<1><<<gg, 256, 0, stream>>>(attnb, wob, d_out, 8192, 1024, 1024);
}

// Round 2
// 187.877 us; speedup vs baseline: 1.6122x; 1.6122x over previous
//
#include <hip/hip_runtime.h>
#include <cstdint>
#include <cstddef>

typedef unsigned short u16;
typedef __attribute__((ext_vector_type(8))) short short8;
typedef __attribute__((ext_vector_type(4))) short short4v;
typedef __attribute__((ext_vector_type(8))) unsigned short ushort8v;
typedef __attribute__((ext_vector_type(4))) unsigned short ushort4v;
typedef __attribute__((ext_vector_type(4))) unsigned int uint4v;
typedef __attribute__((ext_vector_type(4))) float f32x4;

// Q is pre-scaled by 0.125 * log2(e) in the QKV GEMM epilogue, so softmax
// runs directly in the log2 domain (exp2, no per-element multiplies).
#define QSCALE 0.18033688011112042f
#define THR_L2 11.5417f   /* 8 * log2(e) defer-max threshold (T13) */

// ---- helpers -------------------------------------------------------------

__device__ __forceinline__ u16 f2bf(float f) {
  unsigned int u = __builtin_bit_cast(unsigned int, f);
  u += 0x7FFFu + ((u >> 16) & 1u);   // RNE
  return (u16)(u >> 16);
}

__device__ __forceinline__ void async16(const void* g, void* l) {
  __builtin_amdgcn_global_load_lds(
      (const __attribute__((address_space(1))) unsigned int*)g,
      (__attribute__((address_space(3))) unsigned int*)l, 16, 0, 0);
}

__device__ __forceinline__ float fmax3(float a, float b, float c) {
  float r;
  asm("v_max3_f32 %0, %1, %2, %3" : "=v"(r) : "v"(a), "v"(b), "v"(c));
  return r;
}

__device__ __forceinline__ unsigned int cvtpk(float lo, float hi) {
  unsigned int r;
  asm("v_cvt_pk_bf16_f32 %0, %1, %2" : "=v"(r) : "v"(lo), "v"(hi));
  return r;
}

// ---- fp32 -> bf16 convert ------------------------------------------------

__global__ void cvt_f32_bf16(const float* __restrict__ in, u16* __restrict__ out, int n) {
  int i = (blockIdx.x * 256 + threadIdx.x) * 4;
  if (i >= n) return;
  float4 v = *(const float4*)(in + i);
  ushort4v o;
  o[0] = f2bf(v.x); o[1] = f2bf(v.y); o[2] = f2bf(v.z); o[3] = f2bf(v.w);
  *(ushort4v*)(out + i) = o;
}

__global__ void cvt_w4(const float* __restrict__ a, const float* __restrict__ b,
                       const float* __restrict__ c, const float* __restrict__ d,
                       u16* __restrict__ out) {
  const int i = (blockIdx.x * 256 + threadIdx.x) * 4;
  const float* src = (blockIdx.y == 0) ? a : (blockIdx.y == 1) ? b
                    : (blockIdx.y == 2) ? c : d;
  float4 v = *(const float4*)(src + i);
  ushort4v o;
  o[0] = f2bf(v.x); o[1] = f2bf(v.y); o[2] = f2bf(v.z); o[3] = f2bf(v.w);
  *(ushort4v*)(out + (size_t)blockIdx.y * 1048576 + i) = o;
}

// ---- bf16 GEMM: C[M,N] = A[M,K] * W[N,K]^T  (m97-style 128^2 tile) -------
// MODE 0: fused QKV — bf16 output permuted to [B,H,S,HD], col>>10 selects
//         the destination matrix (Q gets QSCALE folded in).
// MODE 1: f32 output [M,N].

template<int MODE>
__global__ __launch_bounds__(256, 2) void gemm_bt(
    const u16* __restrict__ A, const u16* __restrict__ Bw,
    void* __restrict__ Cout, int M, int N, int K)
{
  const int t = threadIdx.x;
  const int lane = t & 63, w = t >> 6;
  const int li = lane & 15, g = lane >> 4;
  const int wr = w >> 1, wc = w & 1;
  const int brow = blockIdx.y * 128, bcol = blockIdx.x * 128;

  __shared__ u16 As[128 * 32];
  __shared__ u16 Bs[128 * 32];

  f32x4 acc[4][4];
#pragma unroll
  for (int i = 0; i < 4; ++i)
#pragma unroll
    for (int j = 0; j < 4; ++j) acc[i][j] = f32x4{0.f, 0.f, 0.f, 0.f};

  for (int k0 = 0; k0 < K; k0 += 32) {
#pragma unroll
    for (int L = 0; L < 2; ++L) {
      const int f = t + 256 * L;
      const int row = f >> 2;
      const int cb = ((f & 3) * 16) ^ ((row & 3) << 4);   // swizzled byte-in-row
      async16(A + (size_t)(brow + row) * K + k0 + (cb >> 1),
              &As[(w * 64 + 256 * L) * 8]);
      async16(Bw + (size_t)(bcol + row) * K + k0 + (cb >> 1),
              &Bs[(w * 64 + 256 * L) * 8]);
    }
    __syncthreads();
    short8 af[4], bfr[4];
    const int ksw = (g * 8) ^ ((li & 3) << 3);            // swizzled k-offset (elems)
#pragma unroll
    for (int mt = 0; mt < 4; ++mt)
      af[mt] = *(const short8*)&As[(wr * 64 + mt * 16 + li) * 32 + ksw];
#pragma unroll
    for (int nt = 0; nt < 4; ++nt)
      bfr[nt] = *(const short8*)&Bs[(wc * 64 + nt * 16 + li) * 32 + ksw];
    __builtin_amdgcn_s_setprio(1);
#pragma unroll
    for (int mt = 0; mt < 4; ++mt)
#pragma unroll
      for (int nt = 0; nt < 4; ++nt)
        acc[mt][nt] = __builtin_amdgcn_mfma_f32_16x16x32_bf16(af[mt], bfr[nt], acc[mt][nt], 0, 0, 0);
    __builtin_amdgcn_s_setprio(0);
    __syncthreads();
  }

#pragma unroll
  for (int mt = 0; mt < 4; ++mt)
#pragma unroll
    for (int nt = 0; nt < 4; ++nt) {
      const int col = bcol + wc * 64 + nt * 16 + li;
#pragma unroll
      for (int r = 0; r < 4; ++r) {
        const int row = brow + wr * 64 + mt * 16 + g * 4 + r;
        float v = acc[mt][nt][r];
        if (MODE == 0) {
          const int which = col >> 10;       // 0=Q 1=K 2=V
          const int c2 = col & 1023;
          if (which == 0) v *= QSCALE;
          const int b = row >> 11, s = row & 2047;
          const int h = c2 >> 6, hd = c2 & 63;
          ((u16*)Cout)[(size_t)which * 8388608 +
                       (((size_t)(b * 16 + h) * 2048) + s) * 64 + hd] = f2bf(v);
        } else {
          ((float*)Cout)[(size_t)row * N + col] = v;
        }
      }
    }
}

// ---- V [B,H,S,HD] -> VT [B,H,HD,S] ---------------------------------------

__global__ __launch_bounds__(256) void transpose_hd_s(
    const u16* __restrict__ V, u16* __restrict__ VT)
{
  const int sb = blockIdx.x;
  const int bh = blockIdx.y;
  __shared__ u16 tile[64 * 72];
  const int t = threadIdx.x;
  const int r = t >> 3;
  const int c8 = (t & 7) * 8;
  const size_t base = (size_t)bh * 2048 * 64;
#pragma unroll
  for (int half = 0; half < 2; ++half) {
    const int row = r + 32 * half;
    ushort8v v = *(const ushort8v*)(V + base + (size_t)(sb * 64 + row) * 64 + c8);
    *(ushort8v*)&tile[row * 72 + c8] = v;
  }
  __syncthreads();
#pragma unroll
  for (int half = 0; half < 2; ++half) {
    const int hd = r + 32 * half;
    ushort8v o;
#pragma unroll
    for (int j = 0; j < 8; ++j) o[j] = tile[(c8 + j) * 72 + hd];
    *(ushort8v*)(VT + base + (size_t)hd * 2048 + sb * 64 + c8) = o;
  }
}

// ---- causal flash attention, QBLK=128 (2 q-subtiles per wave) ------------
// Q,K: [B,H,S,HD] bf16 (Q pre-scaled by QSCALE)   VT: [B,H,HD,S] bf16
// S^T = mfma(K, Q): lane owns q-rows (qs, li); kf/vf shared across qs.

__global__ __launch_bounds__(256, 4) void flash_attn2(
    const u16* __restrict__ Qp, const u16* __restrict__ Kp,
    const u16* __restrict__ VTp, u16* __restrict__ Oattn)
{
  // balanced qb assignment: ids ≡ c (mod 256) get qb sets {p,3-p',..} whose
  // iteration counts sum equally (68) on every CU; all 4 share one bh.
  const int n = blockIdx.x;
  const int p4 = n & 3;
  const int bh = (n >> 2) & 63;
  const int t4 = n >> 8;
  int qb;
  if (t4 == 0) qb = p4;
  else if (t4 == 1) qb = 4 + (3 - p4);
  else if (t4 == 2) qb = 8 + (p4 ^ 1);
  else qb = 12 + (p4 ^ 2);

  const int t = threadIdx.x;
  const int lane = t & 63, w = t >> 6;
  const int li = lane & 15, g = lane >> 4;

  __shared__ u16 Kl[64 * 64];   // [kv][hd], rows 128B, XOR-swizzled
  __shared__ u16 Vl[64 * 64];   // [hd][kv], rows 128B, XOR-swizzled

  const size_t bh_off = (size_t)bh * (2048 * 64);

  short8 qf[2][2];
  int qrow[2];
#pragma unroll
  for (int qs = 0; qs < 2; ++qs) {
    qrow[qs] = qb * 128 + qs * 64 + w * 16 + li;
    const u16* qp = Qp + bh_off + (size_t)qrow[qs] * 64 + g * 8;
    qf[qs][0] = *(const short8*)qp;
    qf[qs][1] = *(const short8*)(qp + 32);
  }

  f32x4 o_acc[2][4];
#pragma unroll
  for (int qs = 0; qs < 2; ++qs)
#pragma unroll
    for (int i = 0; i < 4; ++i) o_acc[qs][i] = f32x4{0.f, 0.f, 0.f, 0.f};
  float m_i[2] = {-1e30f, -1e30f};
  float l_i[2] = {0.f, 0.f};

  const int njb = 2 * qb + 2;
  for (int jb = 0; jb < njb; ++jb) {
#pragma unroll
    for (int L = 0; L < 2; ++L) {
      const int f = t + 256 * L;
      const int kbyte = (f * 16) ^ (((f >> 3) & 7) << 4);
      async16(Kp + bh_off + (size_t)jb * 4096 + (kbyte >> 1),
              &Kl[(w * 64 + 256 * L) * 8]);
      const int vrow = f >> 3;
      const int vb = ((f & 7) * 16) ^ ((vrow & 7) << 4);
      async16(VTp + bh_off + (size_t)vrow * 2048 + jb * 64 + (vb >> 1),
              &Vl[(w * 64 + 256 * L) * 8]);
    }
    __syncthreads();

    // ---- S^T = K * Q^T for both q-subtiles (kf read once)
    f32x4 s_acc[2][4];
#pragma unroll
    for (int qs = 0; qs < 2; ++qs)
#pragma unroll
      for (int jt = 0; jt < 4; ++jt) s_acc[qs][jt] = f32x4{0.f, 0.f, 0.f, 0.f};
    const int ksw = (li & 7) << 3;
    __builtin_amdgcn_s_setprio(1);
#pragma unroll
    for (int kc = 0; kc < 2; ++kc)
#pragma unroll
      for (int jt = 0; jt < 4; ++jt) {
        short8 kf = *(const short8*)&Kl[(jt * 16 + li) * 64 + ((kc * 32 + g * 8) ^ ksw)];
        s_acc[0][jt] = __builtin_amdgcn_mfma_f32_16x16x32_bf16(kf, qf[0][kc], s_acc[0][jt], 0, 0, 0);
        s_acc[1][jt] = __builtin_amdgcn_mfma_f32_16x16x32_bf16(kf, qf[1][kc], s_acc[1][jt], 0, 0, 0);
      }
    __builtin_amdgcn_s_setprio(0);

    // ---- causal mask + row max (log2 domain, scale pre-folded into Q)
    float mx[2];
    bool need = false;
#pragma unroll
    for (int qs = 0; qs < 2; ++qs) {
      if (jb * 64 + 63 > qb * 128 + qs * 64 + w * 16) {   // wave-uniform
        const int tq = qrow[qs] - jb * 64;
#pragma unroll
        for (int jt = 0; jt < 4; ++jt)
#pragma unroll
          for (int r = 0; r < 4; ++r)
            if (jt * 16 + g * 4 + r > tq) s_acc[qs][jt][r] = -1e30f;
      }
      float t0 = fmax3(s_acc[qs][0][0], s_acc[qs][0][1], s_acc[qs][0][2]);
      float t1 = fmax3(s_acc[qs][0][3], s_acc[qs][1][0], s_acc[qs][1][1]);
      float t2 = fmax3(s_acc[qs][1][2], s_acc[qs][1][3], s_acc[qs][2][0]);
      float t3 = fmax3(s_acc[qs][2][1], s_acc[qs][2][2], s_acc[qs][2][3]);
      float t4m = fmax3(s_acc[qs][3][0], s_acc[qs][3][1], s_acc[qs][3][2]);
      float m01 = fmax3(t0, t1, s_acc[qs][3][3]);
      float m23 = fmax3(t2, t3, t4m);
      float mm = fmaxf(m01, m23);
      mm = fmaxf(mm, __shfl_xor(mm, 16));
      mm = fmaxf(mm, __shfl_xor(mm, 32));
      mx[qs] = mm;
      need = need || (mm > m_i[qs] + THR_L2);
    }

    // ---- defer-max rescale (T13)
    if (__any((int)need)) {
#pragma unroll
      for (int qs = 0; qs < 2; ++qs) {
        const float mn = fmaxf(m_i[qs], mx[qs]);
        const float corr = __builtin_amdgcn_exp2f(m_i[qs] - mn);
        l_i[qs] *= corr;
#pragma unroll
        for (int dt = 0; dt < 4; ++dt) o_acc[qs][dt] *= corr;
        m_i[qs] = mn;
      }
    }

    // ---- P = exp2(S - m), row sum, pack to bf16 fragments
    short8 pf[2][2];
#pragma unroll
    for (int qs = 0; qs < 2; ++qs) {
      const float mi = m_i[qs];
      float ps = 0.f;
#pragma unroll
      for (int jt = 0; jt < 4; ++jt)
#pragma unroll
        for (int r = 0; r < 4; ++r) {
          float e = __builtin_amdgcn_exp2f(s_acc[qs][jt][r] - mi);
          s_acc[qs][jt][r] = e;
          ps += e;
        }
      ps += __shfl_xor(ps, 16);
      ps += __shfl_xor(ps, 32);
      l_i[qs] += ps;
#pragma unroll
      for (int kc = 0; kc < 2; ++kc) {
        uint4v u;
        u[0] = cvtpk(s_acc[qs][2 * kc][0], s_acc[qs][2 * kc][1]);
        u[1] = cvtpk(s_acc[qs][2 * kc][2], s_acc[qs][2 * kc][3]);
        u[2] = cvtpk(s_acc[qs][2 * kc + 1][0], s_acc[qs][2 * kc + 1][1]);
        u[3] = cvtpk(s_acc[qs][2 * kc + 1][2], s_acc[qs][2 * kc + 1][3]);
        pf[qs][kc] = __builtin_bit_cast(short8, u);
      }
    }

    // ---- O^T += V^T * P^T for both q-subtiles (vf read once)
    __builtin_amdgcn_s_setprio(1);
#pragma unroll
    for (int kc = 0; kc < 2; ++kc)
#pragma unroll
      for (int dt = 0; dt < 4; ++dt) {
        const int rowb = (dt * 16 + li) * 64;
        short4v v0 = *(const short4v*)&Vl[rowb + ((kc * 32 + g * 4) ^ ksw)];
        short4v v1 = *(const short4v*)&Vl[rowb + ((kc * 32 + 16 + g * 4) ^ ksw)];
        short8 vf = __builtin_shufflevector(v0, v1, 0, 1, 2, 3, 4, 5, 6, 7);
        o_acc[0][dt] = __builtin_amdgcn_mfma_f32_16x16x32_bf16(vf, pf[0][kc], o_acc[0][dt], 0, 0, 0);
        o_acc[1][dt] = __builtin_amdgcn_mfma_f32_16x16x32_bf16(vf, pf[1][kc], o_acc[1][dt], 0, 0, 0);
      }
    __builtin_amdgcn_s_setprio(0);
    __syncthreads();
  }

  // ---- epilogue
  const int b = bh >> 4, h = bh & 15;
#pragma unroll
  for (int qs = 0; qs < 2; ++qs) {
    const float inv_l = 1.f / l_i[qs];
    u16* op = Oattn + ((size_t)(b * 2048 + qrow[qs])) * 1024 + h * 64;
#pragma unroll
    for (int dt = 0; dt < 4; ++dt) {
      ushort4v st;
#pragma unroll
      for (int r = 0; r < 4; ++r) st[r] = f2bf(o_acc[qs][dt][r] * inv_l);
      *(ushort4v*)(op + dt * 16 + g * 4) = st;
    }
  }
}

// ---- launch --------------------------------------------------------------

extern "C" void kernel_launch(void* const* d_in, const int* in_sizes, int n_in,
                              void* d_out, int out_size, void* d_ws, size_t ws_size,
                              hipStream_t stream) {
  const float* x  = (const float*)d_in[0];
  const float* Wq = (const float*)d_in[1];
  const float* Wk = (const float*)d_in[2];
  const float* Wv = (const float*)d_in[3];
  const float* Wo = (const float*)d_in[4];

  const size_t NX = 8388608;   // B*S*D
  const size_t NW = 1048576;   // D*D

  u16* xb  = (u16*)d_ws;
  u16* wqb = xb + NX;          // wq|wk|wv|wo contiguous
  u16* wob = wqb + 3 * NW;
  u16* Qb  = wob + NW;
  u16* Kb  = Qb + NX;
  u16* Vb  = Kb + NX;
  u16* VTb = Vb + NX;
  u16* attnb = Vb;             // V natural is dead after transpose; reuse

  cvt_f32_bf16<<<8192, 256, 0, stream>>>(x, xb, (int)NX);
  cvt_w4<<<dim3(1024, 4), 256, 0, stream>>>(Wq, Wk, Wv, Wo, wqb);

  // fused QKV projection: W rows stacked [3072, 1024]
  gemm_bt<0><<<dim3(24, 64), 256, 0, stream>>>(xb, wqb, Qb, 8192, 3072, 1024);

  transpose_hd_s<<<dim3(32, 64), 256, 0, stream>>>(Vb, VTb);
  flash_attn2<<<1024, 256, 0, stream>>>(Qb, Kb, VTb, attnb);

  gemm_bt<1><<<dim3(8, 64), 256, 0, stream>>>(attnb, wob, d_out, 8192, 1024, 1024);
}

// Round 3
// 183.416 us; speedup vs baseline: 1.6514x; 1.0243x over previous
//
#include <hip/hip_runtime.h>
#include <cstdint>
#include <cstddef>

typedef unsigned short u16;
typedef __attribute__((ext_vector_type(8))) short short8;
typedef __attribute__((ext_vector_type(4))) short short4v;
typedef __attribute__((ext_vector_type(8))) unsigned short ushort8v;
typedef __attribute__((ext_vector_type(4))) unsigned short ushort4v;
typedef __attribute__((ext_vector_type(4))) unsigned int uint4v;
typedef __attribute__((ext_vector_type(4))) float f32x4;

// Q is pre-scaled by 0.125 * log2(e) in the QKV GEMM epilogue, so softmax
// runs directly in the log2 domain (exp2, no per-element multiplies).
#define QSCALE 0.18033688011112042f
#define THR_L2 11.5417f   /* 8 * log2(e) defer-max threshold (T13) */

// ---- helpers -------------------------------------------------------------

__device__ __forceinline__ u16 f2bf(float f) {
  unsigned int u = __builtin_bit_cast(unsigned int, f);
  u += 0x7FFFu + ((u >> 16) & 1u);   // RNE
  return (u16)(u >> 16);
}

__device__ __forceinline__ void async16(const void* g, void* l) {
  __builtin_amdgcn_global_load_lds(
      (const __attribute__((address_space(1))) unsigned int*)g,
      (__attribute__((address_space(3))) unsigned int*)l, 16, 0, 0);
}

__device__ __forceinline__ float fmax3(float a, float b, float c) {
  float r;
  asm("v_max3_f32 %0, %1, %2, %3" : "=v"(r) : "v"(a), "v"(b), "v"(c));
  return r;
}

__device__ __forceinline__ unsigned int cvtpk(float lo, float hi) {
  unsigned int r;
  asm("v_cvt_pk_bf16_f32 %0, %1, %2" : "=v"(r) : "v"(lo), "v"(hi));
  return r;
}

// ---- fp32 -> bf16 convert ------------------------------------------------

__global__ void cvt_f32_bf16(const float* __restrict__ in, u16* __restrict__ out, int n) {
  int i = (blockIdx.x * 256 + threadIdx.x) * 4;
  if (i >= n) return;
  float4 v = *(const float4*)(in + i);
  ushort4v o;
  o[0] = f2bf(v.x); o[1] = f2bf(v.y); o[2] = f2bf(v.z); o[3] = f2bf(v.w);
  *(ushort4v*)(out + i) = o;
}

__global__ void cvt_w4(const float* __restrict__ a, const float* __restrict__ b,
                       const float* __restrict__ c, const float* __restrict__ d,
                       u16* __restrict__ out) {
  const int i = (blockIdx.x * 256 + threadIdx.x) * 4;
  const float* src = (blockIdx.y == 0) ? a : (blockIdx.y == 1) ? b
                    : (blockIdx.y == 2) ? c : d;
  float4 v = *(const float4*)(src + i);
  ushort4v o;
  o[0] = f2bf(v.x); o[1] = f2bf(v.y); o[2] = f2bf(v.z); o[3] = f2bf(v.w);
  *(ushort4v*)(out + (size_t)blockIdx.y * 1048576 + i) = o;
}

// ---- bf16 GEMM: C[M,N] = A[M,K] * W[N,K]^T  (m97-style 128^2 tile) -------
// MODE 0: fused QKV — bf16 output permuted to [B,H,S,HD], col>>10 selects
//         the destination matrix (Q gets QSCALE folded in).
// MODE 1: f32 output [M,N].

template<int MODE>
__global__ __launch_bounds__(256, 2) void gemm_bt(
    const u16* __restrict__ A, const u16* __restrict__ Bw,
    void* __restrict__ Cout, int M, int N, int K)
{
  const int t = threadIdx.x;
  const int lane = t & 63, w = t >> 6;
  const int li = lane & 15, g = lane >> 4;
  const int wr = w >> 1, wc = w & 1;

  // T1: XCD-aware block swizzle (nwg % 8 == 0 for all our launches)
  const int nx = gridDim.x;
  const int hwid = blockIdx.y * nx + blockIdx.x;
  const int cpx = (nx * gridDim.y) >> 3;
  const int lid = (hwid & 7) * cpx + (hwid >> 3);
  const int brow = (lid / nx) * 128, bcol = (lid % nx) * 128;

  __shared__ u16 As[128 * 32];
  __shared__ u16 Bs[128 * 32];

  f32x4 acc[4][4];
#pragma unroll
  for (int i = 0; i < 4; ++i)
#pragma unroll
    for (int j = 0; j < 4; ++j) acc[i][j] = f32x4{0.f, 0.f, 0.f, 0.f};

  for (int k0 = 0; k0 < K; k0 += 32) {
#pragma unroll
    for (int L = 0; L < 2; ++L) {
      const int f = t + 256 * L;
      const int row = f >> 2;
      const int cb = ((f & 3) * 16) ^ ((row & 3) << 4);   // swizzled byte-in-row
      async16(A + (size_t)(brow + row) * K + k0 + (cb >> 1),
              &As[(w * 64 + 256 * L) * 8]);
      async16(Bw + (size_t)(bcol + row) * K + k0 + (cb >> 1),
              &Bs[(w * 64 + 256 * L) * 8]);
    }
    __syncthreads();
    short8 af[4], bfr[4];
    const int ksw = (g * 8) ^ ((li & 3) << 3);            // swizzled k-offset (elems)
#pragma unroll
    for (int mt = 0; mt < 4; ++mt)
      af[mt] = *(const short8*)&As[(wr * 64 + mt * 16 + li) * 32 + ksw];
#pragma unroll
    for (int nt = 0; nt < 4; ++nt)
      bfr[nt] = *(const short8*)&Bs[(wc * 64 + nt * 16 + li) * 32 + ksw];
    __builtin_amdgcn_s_setprio(1);
#pragma unroll
    for (int mt = 0; mt < 4; ++mt)
#pragma unroll
      for (int nt = 0; nt < 4; ++nt)
        acc[mt][nt] = __builtin_amdgcn_mfma_f32_16x16x32_bf16(af[mt], bfr[nt], acc[mt][nt], 0, 0, 0);
    __builtin_amdgcn_s_setprio(0);
    __syncthreads();
  }

#pragma unroll
  for (int mt = 0; mt < 4; ++mt)
#pragma unroll
    for (int nt = 0; nt < 4; ++nt) {
      const int col = bcol + wc * 64 + nt * 16 + li;
#pragma unroll
      for (int r = 0; r < 4; ++r) {
        const int row = brow + wr * 64 + mt * 16 + g * 4 + r;
        float v = acc[mt][nt][r];
        if (MODE == 0) {
          const int which = col >> 10;       // 0=Q 1=K 2=V
          const int c2 = col & 1023;
          if (which == 0) v *= QSCALE;
          const int b = row >> 11, s = row & 2047;
          const int h = c2 >> 6, hd = c2 & 63;
          ((u16*)Cout)[(size_t)which * 8388608 +
                       (((size_t)(b * 16 + h) * 2048) + s) * 64 + hd] = f2bf(v);
        } else {
          ((float*)Cout)[(size_t)row * N + col] = v;
        }
      }
    }
}

// ---- V [B,H,S,HD] -> VT [B,H,HD,S] ---------------------------------------

__global__ __launch_bounds__(256) void transpose_hd_s(
    const u16* __restrict__ V, u16* __restrict__ VT)
{
  const int sb = blockIdx.x;
  const int bh = blockIdx.y;
  __shared__ u16 tile[64 * 72];
  const int t = threadIdx.x;
  const int r = t >> 3;
  const int c8 = (t & 7) * 8;
  const size_t base = (size_t)bh * 2048 * 64;
#pragma unroll
  for (int half = 0; half < 2; ++half) {
    const int row = r + 32 * half;
    ushort8v v = *(const ushort8v*)(V + base + (size_t)(sb * 64 + row) * 64 + c8);
    *(ushort8v*)&tile[row * 72 + c8] = v;
  }
  __syncthreads();
#pragma unroll
  for (int half = 0; half < 2; ++half) {
    const int hd = r + 32 * half;
    ushort8v o;
#pragma unroll
    for (int j = 0; j < 8; ++j) o[j] = tile[(c8 + j) * 72 + hd];
    *(ushort8v*)(VT + base + (size_t)hd * 2048 + sb * 64 + c8) = o;
  }
}

// ---- causal flash attention v3 -------------------------------------------
// Equal-work pairing: block handles q-tiles (p, 15-p)  => 34 kv-iters each.
// Triple-buffered K/V LDS + counted vmcnt(4) + raw barriers (T3/T4-minimum).
// S^T = mfma(K, Q): lane owns q-row (qs, li); kf/vf shared across qs.

__global__ __launch_bounds__(256, 2) void flash_attn3(
    const u16* __restrict__ Qp, const u16* __restrict__ Kp,
    const u16* __restrict__ VTp, u16* __restrict__ Oattn)
{
  // T1: 8 consecutive bh per XCD (K/V working set ~4MB = one L2)
  const int hwid = blockIdx.x;                 // 0..511
  const int lid = (hwid & 7) * 64 + (hwid >> 3);
  const int pr = lid & 7, bh = lid >> 3;

  const int t = threadIdx.x;
  const int lane = t & 63, w = t >> 6;
  const int li = lane & 15, g = lane >> 4;

  __shared__ u16 Kl[3][64 * 64];   // [buf][kv][hd], rows 128B, XOR-swizzled
  __shared__ u16 Vl[3][64 * 64];   // [buf][hd][kv]

  const size_t bh_off = (size_t)bh * (2048 * 64);
  const int tile0 = pr, tile1 = 15 - pr;
  const int njb0 = 2 * tile0 + 2;              // iters in segment 0 (total 34)

  // ---- Q fragments for BOTH tiles up-front (static indexing only)
  short8 qf0[2][2], qf1[2][2];
#pragma unroll
  for (int qs = 0; qs < 2; ++qs) {
    const u16* qp0 = Qp + bh_off + (size_t)(tile0 * 128 + qs * 64 + w * 16 + li) * 64 + g * 8;
    qf0[qs][0] = *(const short8*)qp0;
    qf0[qs][1] = *(const short8*)(qp0 + 32);
    const u16* qp1 = Qp + bh_off + (size_t)(tile1 * 128 + qs * 64 + w * 16 + li) * 64 + g * 8;
    qf1[qs][0] = *(const short8*)qp1;
    qf1[qs][1] = *(const short8*)(qp1 + 32);
  }
  short8 qc[2][2];                              // current tile's Q
#pragma unroll
  for (int qs = 0; qs < 2; ++qs) { qc[qs][0] = qf0[qs][0]; qc[qs][1] = qf0[qs][1]; }

  int qbase = tile0 * 128;

  f32x4 o_acc[2][4];
#pragma unroll
  for (int qs = 0; qs < 2; ++qs)
#pragma unroll
    for (int i = 0; i < 4; ++i) o_acc[qs][i] = f32x4{0.f, 0.f, 0.f, 0.f};
  float m_i[2] = {-1e30f, -1e30f};
  float l_i[2] = {0.f, 0.f};

  const int b = bh >> 4, h = bh & 15;
  const int ksw = (li & 7) << 3;

  auto STAGE = [&](int i, int s) {
    const int jb = (i < njb0) ? i : (i - njb0);
#pragma unroll
    for (int L = 0; L < 2; ++L) {
      const int f = t + 256 * L;
      const int kbyte = (f * 16) ^ (((f >> 3) & 7) << 4);
      async16(Kp + bh_off + (size_t)jb * 4096 + (kbyte >> 1),
              &Kl[s][(w * 64 + 256 * L) * 8]);
      const int vrow = f >> 3;
      const int vb = ((f & 7) * 16) ^ ((vrow & 7) << 4);
      async16(VTp + bh_off + (size_t)vrow * 2048 + jb * 64 + (vb >> 1),
              &Vl[s][(w * 64 + 256 * L) * 8]);
    }
  };

  auto WRITEO = [&]() {
#pragma unroll
    for (int qs = 0; qs < 2; ++qs) {
      const float inv_l = 1.f / l_i[qs];
      const int qrow = qbase + qs * 64 + w * 16 + li;
      u16* op = Oattn + ((size_t)(b * 2048 + qrow)) * 1024 + h * 64;
#pragma unroll
      for (int dt = 0; dt < 4; ++dt) {
        ushort4v st;
#pragma unroll
        for (int r = 0; r < 4; ++r) st[r] = f2bf(o_acc[qs][dt][r] * inv_l);
        *(ushort4v*)(op + dt * 16 + g * 4) = st;
      }
    }
  };

  // ---- prologue: fill pipeline 2 deep
  STAGE(0, 0);
  STAGE(1, 1);
  asm volatile("s_waitcnt vmcnt(4)" ::: "memory");   // buf0 landed (+q drained)
  __builtin_amdgcn_s_barrier();

#pragma unroll 1
  for (int i = 0; i < 34; ++i) {
    const int s = i % 3;
    if (i + 2 < 34) STAGE(i + 2, (i + 2) % 3);

    const int jb = (i < njb0) ? i : (i - njb0);
    const u16* __restrict__ Ks = &Kl[s][0];
    const u16* __restrict__ Vs = &Vl[s][0];

    // ---- S^T = K * Q^T for both q-subtiles (kf read once)
    f32x4 s_acc[2][4];
#pragma unroll
    for (int qs = 0; qs < 2; ++qs)
#pragma unroll
      for (int jt = 0; jt < 4; ++jt) s_acc[qs][jt] = f32x4{0.f, 0.f, 0.f, 0.f};
    __builtin_amdgcn_s_setprio(1);
#pragma unroll
    for (int kc = 0; kc < 2; ++kc)
#pragma unroll
      for (int jt = 0; jt < 4; ++jt) {
        short8 kf = *(const short8*)&Ks[(jt * 16 + li) * 64 + ((kc * 32 + g * 8) ^ ksw)];
        s_acc[0][jt] = __builtin_amdgcn_mfma_f32_16x16x32_bf16(kf, qc[0][kc], s_acc[0][jt], 0, 0, 0);
        s_acc[1][jt] = __builtin_amdgcn_mfma_f32_16x16x32_bf16(kf, qc[1][kc], s_acc[1][jt], 0, 0, 0);
      }
    __builtin_amdgcn_s_setprio(0);

    // ---- causal mask + row max (log2 domain)
    float mx[2];
    bool need = false;
#pragma unroll
    for (int qs = 0; qs < 2; ++qs) {
      if (jb * 64 + 63 > qbase + qs * 64 + w * 16) {   // wave-uniform
        const int tq = qbase + qs * 64 + w * 16 + li - jb * 64;
#pragma unroll
        for (int jt = 0; jt < 4; ++jt)
#pragma unroll
          for (int r = 0; r < 4; ++r)
            if (jt * 16 + g * 4 + r > tq) s_acc[qs][jt][r] = -1e30f;
      }
      float t0 = fmax3(s_acc[qs][0][0], s_acc[qs][0][1], s_acc[qs][0][2]);
      float t1 = fmax3(s_acc[qs][0][3], s_acc[qs][1][0], s_acc[qs][1][1]);
      float t2 = fmax3(s_acc[qs][1][2], s_acc[qs][1][3], s_acc[qs][2][0]);
      float t3 = fmax3(s_acc[qs][2][1], s_acc[qs][2][2], s_acc[qs][2][3]);
      float t4m = fmax3(s_acc[qs][3][0], s_acc[qs][3][1], s_acc[qs][3][2]);
      float m01 = fmax3(t0, t1, s_acc[qs][3][3]);
      float m23 = fmax3(t2, t3, t4m);
      float mm = fmaxf(m01, m23);
      mm = fmaxf(mm, __shfl_xor(mm, 16));
      mm = fmaxf(mm, __shfl_xor(mm, 32));
      mx[qs] = mm;
      need = need || (mm > m_i[qs] + THR_L2);
    }

    // ---- defer-max rescale (T13)
    if (__any((int)need)) {
#pragma unroll
      for (int qs = 0; qs < 2; ++qs) {
        const float mn = fmaxf(m_i[qs], mx[qs]);
        const float corr = __builtin_amdgcn_exp2f(m_i[qs] - mn);
        l_i[qs] *= corr;
#pragma unroll
        for (int dt = 0; dt < 4; ++dt) o_acc[qs][dt] *= corr;
        m_i[qs] = mn;
      }
    }

    // ---- P = exp2(S - m), row sum, pack to bf16 fragments
    short8 pf[2][2];
#pragma unroll
    for (int qs = 0; qs < 2; ++qs) {
      const float mi = m_i[qs];
      float ps = 0.f;
#pragma unroll
      for (int jt = 0; jt < 4; ++jt)
#pragma unroll
        for (int r = 0; r < 4; ++r) {
          float e = __builtin_amdgcn_exp2f(s_acc[qs][jt][r] - mi);
          s_acc[qs][jt][r] = e;
          ps += e;
        }
      ps += __shfl_xor(ps, 16);
      ps += __shfl_xor(ps, 32);
      l_i[qs] += ps;
#pragma unroll
      for (int kc = 0; kc < 2; ++kc) {
        uint4v u;
        u[0] = cvtpk(s_acc[qs][2 * kc][0], s_acc[qs][2 * kc][1]);
        u[1] = cvtpk(s_acc[qs][2 * kc][2], s_acc[qs][2 * kc][3]);
        u[2] = cvtpk(s_acc[qs][2 * kc + 1][0], s_acc[qs][2 * kc + 1][1]);
        u[3] = cvtpk(s_acc[qs][2 * kc + 1][2], s_acc[qs][2 * kc + 1][3]);
        pf[qs][kc] = __builtin_bit_cast(short8, u);
      }
    }

    // ---- O^T += V^T * P^T for both q-subtiles (vf read once)
    __builtin_amdgcn_s_setprio(1);
#pragma unroll
    for (int kc = 0; kc < 2; ++kc)
#pragma unroll
      for (int dt = 0; dt < 4; ++dt) {
        const int rowb = (dt * 16 + li) * 64;
        short4v v0 = *(const short4v*)&Vs[rowb + ((kc * 32 + g * 4) ^ ksw)];
        short4v v1 = *(const short4v*)&Vs[rowb + ((kc * 32 + 16 + g * 4) ^ ksw)];
        short8 vf = __builtin_shufflevector(v0, v1, 0, 1, 2, 3, 4, 5, 6, 7);
        o_acc[0][dt] = __builtin_amdgcn_mfma_f32_16x16x32_bf16(vf, pf[0][kc], o_acc[0][dt], 0, 0, 0);
        o_acc[1][dt] = __builtin_amdgcn_mfma_f32_16x16x32_bf16(vf, pf[1][kc], o_acc[1][dt], 0, 0, 0);
      }
    __builtin_amdgcn_s_setprio(0);

    // ---- end-of-iter sync: LDS reads retired, next buffer landed
    asm volatile("s_waitcnt lgkmcnt(0)" ::: "memory");
    if (i < 32) { asm volatile("s_waitcnt vmcnt(4)" ::: "memory"); }
    else        { asm volatile("s_waitcnt vmcnt(0)" ::: "memory"); }
    __builtin_amdgcn_s_barrier();

    // ---- segment seam: flush tile0, reset state for tile1
    if (i == njb0 - 1) {
      WRITEO();
      qbase = tile1 * 128;
#pragma unroll
      for (int qs = 0; qs < 2; ++qs) {
        qc[qs][0] = qf1[qs][0]; qc[qs][1] = qf1[qs][1];
        m_i[qs] = -1e30f; l_i[qs] = 0.f;
#pragma unroll
        for (int dt = 0; dt < 4; ++dt) o_acc[qs][dt] = f32x4{0.f, 0.f, 0.f, 0.f};
      }
    }
  }

  WRITEO();
}

// ---- launch --------------------------------------------------------------

extern "C" void kernel_launch(void* const* d_in, const int* in_sizes, int n_in,
                              void* d_out, int out_size, void* d_ws, size_t ws_size,
                              hipStream_t stream) {
  const float* x  = (const float*)d_in[0];
  const float* Wq = (const float*)d_in[1];
  const float* Wk = (const float*)d_in[2];
  const float* Wv = (const float*)d_in[3];
  const float* Wo = (const float*)d_in[4];

  const size_t NX = 8388608;   // B*S*D
  const size_t NW = 1048576;   // D*D

  u16* xb  = (u16*)d_ws;
  u16* wqb = xb + NX;          // wq|wk|wv|wo contiguous
  u16* wob = wqb + 3 * NW;
  u16* Qb  = wob + NW;
  u16* Kb  = Qb + NX;
  u16* Vb  = Kb + NX;
  u16* VTb = Vb + NX;
  u16* attnb = Vb;             // V natural is dead after transpose; reuse

  cvt_f32_bf16<<<8192, 256, 0, stream>>>(x, xb, (int)NX);
  cvt_w4<<<dim3(1024, 4), 256, 0, stream>>>(Wq, Wk, Wv, Wo, wqb);

  // fused QKV projection: W rows stacked [3072, 1024]
  gemm_bt<0><<<dim3(24, 64), 256, 0, stream>>>(xb, wqb, Qb, 8192, 3072, 1024);

  transpose_hd_s<<<dim3(32, 64), 256, 0, stream>>>(Vb, VTb);
  flash_attn3<<<512, 256, 0, stream>>>(Qb, Kb, VTb, attnb);

  gemm_bt<1><<<dim3(8, 64), 256, 0, stream>>>(attnb, wob, d_out, 8192, 1024, 1024);
}

// Round 4
// 182.687 us; speedup vs baseline: 1.6580x; 1.0040x over previous
//
#include <hip/hip_runtime.h>
#include <cstdint>
#include <cstddef>

typedef unsigned short u16;
typedef __attribute__((ext_vector_type(8))) short short8;
typedef __attribute__((ext_vector_type(4))) short short4v;
typedef __attribute__((ext_vector_type(8))) unsigned short ushort8v;
typedef __attribute__((ext_vector_type(4))) unsigned short ushort4v;
typedef __attribute__((ext_vector_type(4))) unsigned int uint4v;
typedef __attribute__((ext_vector_type(4))) float f32x4;

// Q is pre-scaled by 0.125 * log2(e) in the QKV GEMM epilogue, so softmax
// runs directly in the log2 domain (exp2, no per-element multiplies).
#define QSCALE 0.18033688011112042f
#define THR_L2 11.5417f   /* 8 * log2(e) defer-max threshold (T13) */

// ---- helpers -------------------------------------------------------------

__device__ __forceinline__ u16 f2bf(float f) {
  unsigned int u = __builtin_bit_cast(unsigned int, f);
  u += 0x7FFFu + ((u >> 16) & 1u);   // RNE
  return (u16)(u >> 16);
}

__device__ __forceinline__ void async16(const void* g, void* l) {
  __builtin_amdgcn_global_load_lds(
      (const __attribute__((address_space(1))) unsigned int*)g,
      (__attribute__((address_space(3))) unsigned int*)l, 16, 0, 0);
}

__device__ __forceinline__ float fmax3(float a, float b, float c) {
  float r;
  asm("v_max3_f32 %0, %1, %2, %3" : "=v"(r) : "v"(a), "v"(b), "v"(c));
  return r;
}

__device__ __forceinline__ unsigned int cvtpk(float lo, float hi) {
  unsigned int r;
  asm("v_cvt_pk_bf16_f32 %0, %1, %2" : "=v"(r) : "v"(lo), "v"(hi));
  return r;
}

// ---- fp32 -> bf16 convert (x + all 4 weights, one launch) ----------------

__global__ void cvt_all(const float* __restrict__ x, const float* __restrict__ Wq,
                        const float* __restrict__ Wk, const float* __restrict__ Wv,
                        const float* __restrict__ Wo, u16* __restrict__ out) {
  const int bid = blockIdx.x;
  const float* src;
  int i;
  size_t doff;
  if (bid < 8192) {               // x: 8.39M elems
    i = bid * 1024 + threadIdx.x * 4;
    src = x;
    doff = (size_t)i;
  } else {                        // weights: 4 x 1M elems
    const int k = bid - 8192;
    const int wsel = k >> 10;
    i = (k & 1023) * 1024 + threadIdx.x * 4;
    src = (wsel == 0) ? Wq : (wsel == 1) ? Wk : (wsel == 2) ? Wv : Wo;
    doff = 8388608 + (size_t)wsel * 1048576 + i;
  }
  float4 v = *(const float4*)(src + i);
  ushort4v o;
  o[0] = f2bf(v.x); o[1] = f2bf(v.y); o[2] = f2bf(v.z); o[3] = f2bf(v.w);
  *(ushort4v*)(out + doff) = o;
}

// ---- bf16 GEMM: C[M,N] = A[M,K] * W[N,K]^T  (m97-style 128^2 tile) -------
// MODE 0: fused QKV — bf16 output permuted to [B,H,S,HD], col>>10 selects
//         the destination matrix (Q gets QSCALE folded in).
// MODE 1: f32 output [M,N].

template<int MODE>
__global__ __launch_bounds__(256, 3) void gemm_bt(
    const u16* __restrict__ A, const u16* __restrict__ Bw,
    void* __restrict__ Cout, int M, int N, int K)
{
  const int t = threadIdx.x;
  const int lane = t & 63, w = t >> 6;
  const int li = lane & 15, g = lane >> 4;
  const int wr = w >> 1, wc = w & 1;

  // T1: XCD-aware block swizzle (nwg % 8 == 0 for all our launches)
  const int nx = gridDim.x;
  const int hwid = blockIdx.y * nx + blockIdx.x;
  const int cpx = (nx * gridDim.y) >> 3;
  const int lid = (hwid & 7) * cpx + (hwid >> 3);
  const int brow = (lid / nx) * 128, bcol = (lid % nx) * 128;

  __shared__ u16 As[128 * 32];
  __shared__ u16 Bs[128 * 32];

  f32x4 acc[4][4];
#pragma unroll
  for (int i = 0; i < 4; ++i)
#pragma unroll
    for (int j = 0; j < 4; ++j) acc[i][j] = f32x4{0.f, 0.f, 0.f, 0.f};

  for (int k0 = 0; k0 < K; k0 += 32) {
#pragma unroll
    for (int L = 0; L < 2; ++L) {
      const int f = t + 256 * L;
      const int row = f >> 2;
      const int cb = ((f & 3) * 16) ^ ((row & 3) << 4);   // swizzled byte-in-row
      async16(A + (size_t)(brow + row) * K + k0 + (cb >> 1),
              &As[(w * 64 + 256 * L) * 8]);
      async16(Bw + (size_t)(bcol + row) * K + k0 + (cb >> 1),
              &Bs[(w * 64 + 256 * L) * 8]);
    }
    __syncthreads();
    short8 af[4], bfr[4];
    const int ksw = (g * 8) ^ ((li & 3) << 3);            // swizzled k-offset (elems)
#pragma unroll
    for (int mt = 0; mt < 4; ++mt)
      af[mt] = *(const short8*)&As[(wr * 64 + mt * 16 + li) * 32 + ksw];
#pragma unroll
    for (int nt = 0; nt < 4; ++nt)
      bfr[nt] = *(const short8*)&Bs[(wc * 64 + nt * 16 + li) * 32 + ksw];
    __builtin_amdgcn_s_setprio(1);
#pragma unroll
    for (int mt = 0; mt < 4; ++mt)
#pragma unroll
      for (int nt = 0; nt < 4; ++nt)
        acc[mt][nt] = __builtin_amdgcn_mfma_f32_16x16x32_bf16(af[mt], bfr[nt], acc[mt][nt], 0, 0, 0);
    __builtin_amdgcn_s_setprio(0);
    __syncthreads();
  }

#pragma unroll
  for (int mt = 0; mt < 4; ++mt)
#pragma unroll
    for (int nt = 0; nt < 4; ++nt) {
      const int col = bcol + wc * 64 + nt * 16 + li;
#pragma unroll
      for (int r = 0; r < 4; ++r) {
        const int row = brow + wr * 64 + mt * 16 + g * 4 + r;
        float v = acc[mt][nt][r];
        if (MODE == 0) {
          const int which = col >> 10;       // 0=Q 1=K 2=V
          const int c2 = col & 1023;
          if (which == 0) v *= QSCALE;
          const int b = row >> 11, s = row & 2047;
          const int h = c2 >> 6, hd = c2 & 63;
          ((u16*)Cout)[(size_t)which * 8388608 +
                       (((size_t)(b * 16 + h) * 2048) + s) * 64 + hd] = f2bf(v);
        } else {
          ((float*)Cout)[(size_t)row * N + col] = v;
        }
      }
    }
}

// ---- V [B,H,S,HD] -> VT [B,H,HD,S] ---------------------------------------

__global__ __launch_bounds__(256) void transpose_hd_s(
    const u16* __restrict__ V, u16* __restrict__ VT)
{
  const int sb = blockIdx.x;
  const int bh = blockIdx.y;
  __shared__ u16 tile[64 * 72];
  const int t = threadIdx.x;
  const int r = t >> 3;
  const int c8 = (t & 7) * 8;
  const size_t base = (size_t)bh * 2048 * 64;
#pragma unroll
  for (int half = 0; half < 2; ++half) {
    const int row = r + 32 * half;
    ushort8v v = *(const ushort8v*)(V + base + (size_t)(sb * 64 + row) * 64 + c8);
    *(ushort8v*)&tile[row * 72 + c8] = v;
  }
  __syncthreads();
#pragma unroll
  for (int half = 0; half < 2; ++half) {
    const int hd = r + 32 * half;
    ushort8v o;
#pragma unroll
    for (int j = 0; j < 8; ++j) o[j] = tile[(c8 + j) * 72 + hd];
    *(ushort8v*)(VT + base + (size_t)hd * 2048 + sb * 64 + c8) = o;
  }
}

// ---- causal flash attention v5 -------------------------------------------
// 64-row q-tiles (32/bh), equal-work pairing (p, 31-p) => every block = 33
// kv-iters (scheduler-proof balance). 2-buffer LDS (32KB) + vmcnt(0)/iter;
// 4-5 resident blocks/CU for TLP. Each wave owns 16 q-rows (single qs).

__global__ __launch_bounds__(256, 5) void flash_attn5(
    const u16* __restrict__ Qp, const u16* __restrict__ Kp,
    const u16* __restrict__ VTp, u16* __restrict__ Oattn)
{
  // T1: 8 consecutive bh per XCD (K/V working set 4MB = one L2)
  const int n = blockIdx.x;                 // 0..1023
  const int xcd = n & 7, sq = n >> 3;       // sq 0..127
  const int bh = xcd * 8 + (sq >> 4);
  const int pr = sq & 15;
  const int tile0 = pr, tile1 = 31 - pr;    // 64-row q-tiles
  const int njb0 = pr + 1;                  // segment-0 iters (total 33)

  const int t = threadIdx.x;
  const int lane = t & 63, w = t >> 6;
  const int li = lane & 15, g = lane >> 4;

  __shared__ u16 Kl[2][4096];   // [buf][kv][hd], rows 128B, XOR-swizzled
  __shared__ u16 Vl[2][4096];   // [buf][hd][kv]

  const size_t bh_off = (size_t)bh * (2048 * 64);
  const int b = bh >> 4, h = bh & 15;
  const int ksw = (li & 7) << 3;

  int qbase = tile0 * 64;

  f32x4 o_acc[4];
#pragma unroll
  for (int i = 0; i < 4; ++i) o_acc[i] = f32x4{0.f, 0.f, 0.f, 0.f};
  float m_i = -1e30f, l_i = 0.f;

  auto STAGE = [&](int i, int sb) {
    const int jb = (i < njb0) ? i : (i - njb0);
#pragma unroll
    for (int L = 0; L < 2; ++L) {
      const int f = t + 256 * L;
      const int kbyte = (f * 16) ^ (((f >> 3) & 7) << 4);
      async16(Kp + bh_off + (size_t)jb * 4096 + (kbyte >> 1),
              &Kl[sb][(w * 64 + 256 * L) * 8]);
      const int vrow = f >> 3;
      const int vb = ((f & 7) * 16) ^ ((vrow & 7) << 4);
      async16(VTp + bh_off + (size_t)vrow * 2048 + jb * 64 + (vb >> 1),
              &Vl[sb][(w * 64 + 256 * L) * 8]);
    }
  };

  auto WRITEO = [&]() {
    const float inv_l = 1.f / l_i;
    const int qrow = qbase + w * 16 + li;
    u16* op = Oattn + ((size_t)(b * 2048 + qrow)) * 1024 + h * 64;
#pragma unroll
    for (int dt = 0; dt < 4; ++dt) {
      ushort4v st;
#pragma unroll
      for (int r = 0; r < 4; ++r) st[r] = f2bf(o_acc[dt][r] * inv_l);
      *(ushort4v*)(op + dt * 16 + g * 4) = st;
    }
  };

  // ---- Q fragment for tile0 (tile1's reloaded at the seam)
  short8 qc[2];
  {
    const u16* qp = Qp + bh_off + (size_t)(qbase + w * 16 + li) * 64 + g * 8;
    qc[0] = *(const short8*)qp;
    qc[1] = *(const short8*)(qp + 32);
  }

  // ---- prologue
  STAGE(0, 0);
  asm volatile("s_waitcnt vmcnt(0)" ::: "memory");
  __builtin_amdgcn_s_barrier();

#pragma unroll 1
  for (int i = 0; i < 33; ++i) {
    const int sb = i & 1;
    if (i + 1 < 33) STAGE(i + 1, (i + 1) & 1);

    const int jb = (i < njb0) ? i : (i - njb0);
    const u16* __restrict__ Ks = &Kl[sb][0];
    const u16* __restrict__ Vs = &Vl[sb][0];

    // ---- S^T = K * Q^T  (lane owns q-row li)
    f32x4 s_acc[4];
#pragma unroll
    for (int jt = 0; jt < 4; ++jt) s_acc[jt] = f32x4{0.f, 0.f, 0.f, 0.f};
    __builtin_amdgcn_s_setprio(1);
#pragma unroll
    for (int kc = 0; kc < 2; ++kc)
#pragma unroll
      for (int jt = 0; jt < 4; ++jt) {
        short8 kf = *(const short8*)&Ks[(jt * 16 + li) * 64 + ((kc * 32 + g * 8) ^ ksw)];
        s_acc[jt] = __builtin_amdgcn_mfma_f32_16x16x32_bf16(kf, qc[kc], s_acc[jt], 0, 0, 0);
      }
    __builtin_amdgcn_s_setprio(0);

    // ---- causal mask + row max (log2 domain)
    if (jb * 64 + 63 > qbase + w * 16) {   // wave-uniform
      const int tq = qbase + w * 16 + li - jb * 64;
#pragma unroll
      for (int jt = 0; jt < 4; ++jt)
#pragma unroll
        for (int r = 0; r < 4; ++r)
          if (jt * 16 + g * 4 + r > tq) s_acc[jt][r] = -1e30f;
    }
    float t0 = fmax3(s_acc[0][0], s_acc[0][1], s_acc[0][2]);
    float t1 = fmax3(s_acc[0][3], s_acc[1][0], s_acc[1][1]);
    float t2 = fmax3(s_acc[1][2], s_acc[1][3], s_acc[2][0]);
    float t3 = fmax3(s_acc[2][1], s_acc[2][2], s_acc[2][3]);
    float t4m = fmax3(s_acc[3][0], s_acc[3][1], s_acc[3][2]);
    float m01 = fmax3(t0, t1, s_acc[3][3]);
    float m23 = fmax3(t2, t3, t4m);
    float mm = fmaxf(m01, m23);
    mm = fmaxf(mm, __shfl_xor(mm, 16));
    mm = fmaxf(mm, __shfl_xor(mm, 32));

    // ---- defer-max rescale (T13)
    if (__any((int)(mm > m_i + THR_L2))) {
      const float mn = fmaxf(m_i, mm);
      const float corr = __builtin_amdgcn_exp2f(m_i - mn);
      l_i *= corr;
#pragma unroll
      for (int dt = 0; dt < 4; ++dt) o_acc[dt] *= corr;
      m_i = mn;
    }

    // ---- P = exp2(S - m), row sum, pack to bf16 fragments
    float ps = 0.f;
#pragma unroll
    for (int jt = 0; jt < 4; ++jt)
#pragma unroll
      for (int r = 0; r < 4; ++r) {
        float e = __builtin_amdgcn_exp2f(s_acc[jt][r] - m_i);
        s_acc[jt][r] = e;
        ps += e;
      }
    ps += __shfl_xor(ps, 16);
    ps += __shfl_xor(ps, 32);
    l_i += ps;
    short8 pf[2];
#pragma unroll
    for (int kc = 0; kc < 2; ++kc) {
      uint4v u;
      u[0] = cvtpk(s_acc[2 * kc][0], s_acc[2 * kc][1]);
      u[1] = cvtpk(s_acc[2 * kc][2], s_acc[2 * kc][3]);
      u[2] = cvtpk(s_acc[2 * kc + 1][0], s_acc[2 * kc + 1][1]);
      u[3] = cvtpk(s_acc[2 * kc + 1][2], s_acc[2 * kc + 1][3]);
      pf[kc] = __builtin_bit_cast(short8, u);
    }

    // ---- O^T += V^T * P^T
    __builtin_amdgcn_s_setprio(1);
#pragma unroll
    for (int kc = 0; kc < 2; ++kc)
#pragma unroll
      for (int dt = 0; dt < 4; ++dt) {
        const int rowb = (dt * 16 + li) * 64;
        short4v v0 = *(const short4v*)&Vs[rowb + ((kc * 32 + g * 4) ^ ksw)];
        short4v v1 = *(const short4v*)&Vs[rowb + ((kc * 32 + 16 + g * 4) ^ ksw)];
        short8 vf = __builtin_shufflevector(v0, v1, 0, 1, 2, 3, 4, 5, 6, 7);
        o_acc[dt] = __builtin_amdgcn_mfma_f32_16x16x32_bf16(vf, pf[kc], o_acc[dt], 0, 0, 0);
      }
    __builtin_amdgcn_s_setprio(0);

    // ---- end-of-iter sync: LDS reads retired, next buffer landed
    asm volatile("s_waitcnt lgkmcnt(0)" ::: "memory");
    asm volatile("s_waitcnt vmcnt(0)" ::: "memory");
    __builtin_amdgcn_s_barrier();

    // ---- segment seam: flush tile0, reload Q, reset state for tile1
    if (i == njb0 - 1) {
      WRITEO();
      qbase = tile1 * 64;
      const u16* qp = Qp + bh_off + (size_t)(qbase + w * 16 + li) * 64 + g * 8;
      qc[0] = *(const short8*)qp;
      qc[1] = *(const short8*)(qp + 32);
      m_i = -1e30f; l_i = 0.f;
#pragma unroll
      for (int dt = 0; dt < 4; ++dt) o_acc[dt] = f32x4{0.f, 0.f, 0.f, 0.f};
    }
  }

  WRITEO();
}

// ---- launch --------------------------------------------------------------

extern "C" void kernel_launch(void* const* d_in, const int* in_sizes, int n_in,
                              void* d_out, int out_size, void* d_ws, size_t ws_size,
                              hipStream_t stream) {
  const float* x  = (const float*)d_in[0];
  const float* Wq = (const float*)d_in[1];
  const float* Wk = (const float*)d_in[2];
  const float* Wv = (const float*)d_in[3];
  const float* Wo = (const float*)d_in[4];

  const size_t NX = 8388608;   // B*S*D
  const size_t NW = 1048576;   // D*D

  u16* xb  = (u16*)d_ws;
  u16* wqb = xb + NX;          // wq|wk|wv|wo contiguous
  u16* wob = wqb + 3 * NW;
  u16* Qb  = wob + NW;
  u16* Kb  = Qb + NX;
  u16* Vb  = Kb + NX;
  u16* VTb = Vb + NX;
  u16* attnb = Vb;             // V natural is dead after transpose; reuse

  cvt_all<<<12288, 256, 0, stream>>>(x, Wq, Wk, Wv, Wo, xb);

  // fused QKV projection: W rows stacked [3072, 1024]
  gemm_bt<0><<<dim3(24, 64), 256, 0, stream>>>(xb, wqb, Qb, 8192, 3072, 1024);

  transpose_hd_s<<<dim3(32, 64), 256, 0, stream>>>(Vb, VTb);
  flash_attn5<<<1024, 256, 0, stream>>>(Qb, Kb, VTb, attnb);

  gemm_bt<1><<<dim3(8, 64), 256, 0, stream>>>(attnb, wob, d_out, 8192, 1024, 1024);
}